// Round 6
// baseline (475.411 us; speedup 1.0000x reference)
//
#include <hip/hip_runtime.h>

#define N_NODES 8192
#define DIM 128

typedef short bf16x8 __attribute__((ext_vector_type(8)));
typedef unsigned short u16x4 __attribute__((ext_vector_type(4)));
typedef float f32x4 __attribute__((ext_vector_type(4)));

__device__ __forceinline__ unsigned short f2bf_rne(float x) {
    unsigned int u = __builtin_bit_cast(unsigned int, x);
    u += 0x7fffu + ((u >> 16) & 1u);   // round-to-nearest-even
    return (unsigned short)(u >> 16);
}
__device__ __forceinline__ float bf2f(unsigned short h) {
    unsigned int u = ((unsigned int)h) << 16;
    return __builtin_bit_cast(float, u);
}

// ---------------- K1: fused rowsum + A -> bf16 fragment-pack ------------
// 512 threads (8 waves) per 16-row block -> 16 waves/CU (4/SIMD) to
// saturate HBM. Streams A in contiguous 2KB row bursts, computes rowsums,
// converts to bf16, packs via XOR-swizzled LDS into MFMA A-fragment order:
//   Abp[rb16][kb][lane][j] = bf16(A[rb16*16 + (lane&15)][kb*32 + (lane>>4)*8 + j])
__global__ __launch_bounds__(512) void k_prep(const float* __restrict__ A,
                                              unsigned short* __restrict__ Abp,
                                              float* __restrict__ d) {
    __shared__ unsigned short tile[16 * 512];   // 16KB, XOR-swizzled bf16 chunk
    __shared__ float rs[4][4][128];             // 8KB rowsum partials
    const int t = threadIdx.x;
    const int lane = t & 63, wv = t >> 6;       // wv 0..7
    const int l15 = lane & 15, quad = lane >> 4;
    const int rb16 = blockIdx.x;
    const float* Ag0 = A + (size_t)rb16 * 16 * N_NODES;
    const int h = t >> 7;              // 0..3: row parity group this thread loads
    const int c4 = (t & 127) << 2;     // f32 col within chunk
    float rsum[4] = {};

    // prologue: chunk 0 loads (rows h+4i, 1KB coalesced per wave)
    f32x4 pre[4];
#pragma unroll
    for (int i = 0; i < 4; ++i)
        pre[i] = *(const f32x4*)(Ag0 + (size_t)(h + 4 * i) * N_NODES + c4);

    for (int chunk = 0; chunk < 16; ++chunk) {
        f32x4 curv[4];
#pragma unroll
        for (int i = 0; i < 4; ++i) curv[i] = pre[i];
        if (chunk < 15) {
            const float* Ag = Ag0 + (chunk + 1) * 512;
#pragma unroll
            for (int i = 0; i < 4; ++i)
                pre[i] = *(const f32x4*)(Ag + (size_t)(h + 4 * i) * N_NODES + c4);
        }
        __syncthreads();               // prior pack-phase reads of tile done
#pragma unroll
        for (int i = 0; i < 4; ++i) {
            int r = h + 4 * i;
            f32x4 v = curv[i];
            rsum[i] += (v[0] + v[1]) + (v[2] + v[3]);
            int byte = (r * 1024 + c4 * 2) ^ ((r & 7) << 4);
            u16x4 pk = { f2bf_rne(v[0]), f2bf_rne(v[1]), f2bf_rne(v[2]), f2bf_rne(v[3]) };
            *(u16x4*)((char*)tile + byte) = pk;
        }
        __syncthreads();
        // pack phase: wave wv handles 2 k-blocks of this chunk
#pragma unroll
        for (int u = 0; u < 2; ++u) {
            int kk = wv * 2 + u;
            int abyte = (l15 * 1024 + (kk * 32 + quad * 8) * 2) ^ ((l15 & 7) << 4);
            bf16x8 frag = *(const bf16x8*)((const char*)tile + abyte);
            int kbg = chunk * 16 + kk;
            *(bf16x8*)(Abp + ((size_t)(rb16 * 256 + kbg) * 64 + lane) * 8) = frag;
        }
    }

    // rowsum: row r = h + 4i partials live in rsum[i] of the 128 threads with t>>7==h
#pragma unroll
    for (int i = 0; i < 4; ++i) rs[h][i][t & 127] = rsum[i];
    __syncthreads();
    if (t < 16) {
        const float* p = rs[t & 3][t >> 2];
        float s = 0.f;
        for (int j = 0; j < 128; ++j) s += p[j];
        d[rb16 * 16 + t] = rsqrtf(s + 1.0f);   // +1 for the identity diagonal
    }
}

// ---------------- K2: Zp = pack_B( bf16( diag(d) * X * W^T ) ) ----------
// B-fragment order: Zp[kb][c16][lane][j] = Z[kb*32 + (lane>>4)*8 + j][c16*16 + (lane&15)]
__global__ __launch_bounds__(256) void k_zgemm(const float* __restrict__ X,
                                               const float* __restrict__ W,
                                               const float* __restrict__ d,
                                               unsigned short* __restrict__ Zp) {
    __shared__ float Xs[64][129];
    __shared__ float Ws[64][129];
    int rb = blockIdx.x >> 1;
    int cb = blockIdx.x & 1;
    int t = threadIdx.x;
    const float4* Xg = (const float4*)(X + (size_t)rb * 64 * DIM);
    const float4* Wg = (const float4*)(W + (size_t)cb * 64 * DIM);
#pragma unroll
    for (int i = 0; i < 8; ++i) {
        int f = t + i * 256;
        int r = f >> 5;
        int c = (f & 31) << 2;
        float4 v = Xg[f];
        Xs[r][c] = v.x; Xs[r][c + 1] = v.y; Xs[r][c + 2] = v.z; Xs[r][c + 3] = v.w;
        float4 w = Wg[f];
        Ws[r][c] = w.x; Ws[r][c + 1] = w.y; Ws[r][c + 2] = w.z; Ws[r][c + 3] = w.w;
    }
    __syncthreads();
    int tx = t & 15, ty = t >> 4;
    float acc[4][4] = {};
    for (int k = 0; k < DIM; ++k) {
        float xr[4], wr[4];
#pragma unroll
        for (int i = 0; i < 4; ++i) xr[i] = Xs[ty * 4 + i][k];
#pragma unroll
        for (int j = 0; j < 4; ++j) wr[j] = Ws[tx * 4 + j][k];
#pragma unroll
        for (int i = 0; i < 4; ++i)
#pragma unroll
            for (int j = 0; j < 4; ++j)
                acc[i][j] += xr[i] * wr[j];
    }
#pragma unroll
    for (int i = 0; i < 4; ++i) {
        int row = rb * 64 + ty * 4 + i;        // node index (k-dim of spmm)
        float dv = d[row];
        int kb = row >> 5, jj = row & 7;
        int lrow = ((row >> 3) & 3) * 16;
#pragma unroll
        for (int j = 0; j < 4; ++j) {
            int col = cb * 64 + tx * 4 + j;    // feature
            int lanep = lrow + (col & 15);
            Zp[((size_t)(kb * 8 + (col >> 4)) * 64 + lanep) * 8 + jj] =
                f2bf_rne(dv * acc[i][j]);
        }
    }
}

// ---------------- K3: out = diag(d) * ((A+I) @ Z) + b -------------------
// Col-split: 512 blocks x 16 rows; wave wv owns col-group wv over the FULL
// K. Zero LDS, zero barriers, wave-local epilogue. af loads are identical
// across the 8 waves -> L1-broadcast. Two accumulator chains for MFMA ILP.
__global__ __launch_bounds__(512) void k_spmm(const unsigned short* __restrict__ Abp,
                                              const unsigned short* __restrict__ Zp,
                                              const float* __restrict__ d,
                                              const float* __restrict__ bias,
                                              float* __restrict__ out) {
    const int t = threadIdx.x;
    const int lane = t & 63, wv = t >> 6;      // wv = col-group 0..7
    const int l15 = lane & 15, quad = lane >> 4;
    const int rb16 = blockIdx.x;
    const int row0 = rb16 * 16;

    const unsigned short* Ab = Abp + ((size_t)rb16 * 256 * 64 + lane) * 8;
    const unsigned short* Zb = Zp + ((size_t)wv * 64 + lane) * 8;

    f32x4 acc0 = {0.f, 0.f, 0.f, 0.f}, acc1 = {0.f, 0.f, 0.f, 0.f};

#pragma unroll 4
    for (int kb = 0; kb < 256; kb += 2) {
        bf16x8 af0 = *(const bf16x8*)(Ab + (size_t)kb * 512);
        bf16x8 b0  = *(const bf16x8*)(Zb + (size_t)kb * 4096);
        bf16x8 af1 = *(const bf16x8*)(Ab + (size_t)(kb + 1) * 512);
        bf16x8 b1  = *(const bf16x8*)(Zb + (size_t)(kb + 1) * 4096);
        acc0 = __builtin_amdgcn_mfma_f32_16x16x32_bf16(af0, b0, acc0, 0, 0, 0);
        acc1 = __builtin_amdgcn_mfma_f32_16x16x32_bf16(af1, b1, acc1, 0, 0, 0);
    }

    int col = wv * 16 + l15;
    float bcol = bias[col];
#pragma unroll
    for (int r = 0; r < 4; ++r) {
        int row = row0 + quad * 4 + r;
        float s = acc0[r] + acc1[r];
        // identity term Z[row][col] gathered from packed Zp
        int kbr = row >> 5, jj = row & 7;
        int lanep = ((row >> 3) & 3) * 16 + l15;
        float zid = bf2f(Zp[((size_t)(kbr * 8 + wv) * 64 + lanep) * 8 + jj]);
        out[(size_t)row * DIM + col] = d[row] * (s + zid) + bcol;
    }
}

extern "C" void kernel_launch(void* const* d_in, const int* in_sizes, int n_in,
                              void* d_out, int out_size, void* d_ws, size_t ws_size,
                              hipStream_t stream) {
    const float* X = (const float*)d_in[0];
    const float* A = (const float*)d_in[1];
    const float* W = (const float*)d_in[2];
    const float* b = (const float*)d_in[3];
    float* out = (float*)d_out;

    char* ws = (char*)d_ws;
    float* dinv = (float*)ws;                               // 32 KB
    unsigned short* Zp = (unsigned short*)(ws + 32768);     // 2 MB  packed Z
    unsigned short* Abp = (unsigned short*)(ws + 32768 + (2u << 20)); // 128 MB packed A

    k_prep<<<512, 512, 0, stream>>>(A, Abp, dinv);
    k_zgemm<<<256, 256, 0, stream>>>(X, W, dinv, Zp);
    k_spmm<<<512, 512, 0, stream>>>(Abp, Zp, dinv, b, out);
}